// Round 13
// baseline (138.317 us; speedup 1.0000x reference)
//
#include <hip/hip_runtime.h>
#include <math.h>

// Problem constants: B=64, T=2000, V=29, L=200
#define Bn 64
#define Tn 2000
#define Vn 29
#define Ln 200
#define Sn 401              // 2L+1 lattice states
#define BLANKC 28
#define EPSF  1e-7f
#define CHUNK 128           // time steps of linear probs per LDS buffer
#define TSTR  132           // floats per symbol row (128 + pad, quad-aligned)
#define SENT  (-(1 << 20))  // exponent sentinel for all-zero lanes
#define LN2F  0.69314718055994531f

typedef float f2 __attribute__((ext_vector_type(2)));

__device__ __forceinline__ float getc(const float4& v, int u) {
    return u == 0 ? v.x : u == 1 ? v.y : u == 2 ? v.z : v.w;
}
__device__ __forceinline__ f2 pair2(const float4& a, const float4& b, int u) {
    return (f2){getc(a, u), getc(b, u)};
}
__device__ __forceinline__ f2 max2(f2 a, f2 b) {
    return (f2){fmaxf(a.x, b.x), fmaxf(a.y, b.y)};
}
// Full-wave DPP shift: lane i <- lane i-1, bound_ctrl zero-fills lane 0.
__device__ __forceinline__ float dpp_shr1_f(float x) {
    return __int_as_float(__builtin_amdgcn_update_dpp(
        0, __float_as_int(x), 0x138, 0xF, 0xF, true));
}
__device__ __forceinline__ int dpp_shr1_i(int x) {
    return __builtin_amdgcn_update_dpp(0, x, 0x138, 0xF, 0xF, true);
}
__device__ __forceinline__ f2 dpp_shr1_f2(f2 v) {
    return (f2){dpp_shr1_f(v.x), dpp_shr1_f(v.y)};
}
// 2^d for d in [-126,0]; anything else returns exactly 0 (flush semantics).
__device__ __forceinline__ float dscale(int d) {
    return (d > 0 || d < -126) ? 0.f : __int_as_float((127 + d) << 23);
}

// ===== packed round pieces: .x = forward alpha, .y = gamma on reversed lattice
#define ALIGN2_                                                                   \
  const int EeF_ = zf_f ? SENT : E_f;                                             \
  const int EeG_ = zf_g ? SENT : E_g;                                             \
  const int EnF_ = max(EeF_, Enb_f);                                              \
  const int EnG_ = max(EeG_, Enb_g);                                              \
  const f2 sb2_ = (f2){dscale(Enb_f - EnF_), dscale(Enb_g - EnG_)};               \
  const f2 sn2_ = (f2){dscale(EeF_ - EnF_),  dscale(EeG_ - EnG_)};                \
  f2 w[16];                                                                       \
  _Pragma("unroll") for (int k = 0; k < 8; ++k) w[k]     = nb2v[k] * sb2_;        \
  _Pragma("unroll") for (int k = 0; k < 8; ++k) w[8 + k] = a2[k]  * sn2_;

#define PREF2_(POUTF, POUTG, PCF, PCG, TOFFN)                                     \
  { const int tf_ = (TOFFN) > (CHUNK-4) ? (CHUNK-4) : (TOFFN);                    \
    _Pragma("unroll") for (int kk = 0; kk < 7; ++kk) {                            \
      POUTF[kk] = *(const float4*)((PCF) + soffF[kk] + tf_);                      \
      POUTG[kk] = *(const float4*)((PCG) + soffG[kk] + tf_); }                    \
    POUTF[7] = *(const float4*)((PCF) + BLANKC * TSTR + tf_);                     \
    POUTG[7] = *(const float4*)((PCG) + BLANKC * TSTR + tf_); }

#define STEP2_(PINF, PING, u)                                                     \
  _Pragma("unroll") for (int ii = 0; ii < 14 - 2 * (u); ++ii) {                   \
    const int i = 15 - ii;                                                        \
    if (i & 1) {                                                                  \
      const int kk = (i - 3) >> 1;                                                \
      w[i] = (w[i] + w[i-1] + sk2[kk] * w[i-2]) * pair2(PINF[kk], PING[kk], u);   \
    } else {                                                                      \
      w[i] = (w[i] + w[i-1]) * pair2(PINF[7], PING[7], u);                        \
    } }

#define STEP2M_(PINF, PING, u, OKF, OKG)                                          \
  _Pragma("unroll") for (int ii = 0; ii < 14 - 2 * (u); ++ii) {                   \
    const int i = 15 - ii;                                                        \
    f2 n_;                                                                        \
    if (i & 1) {                                                                  \
      const int kk = (i - 3) >> 1;                                                \
      n_ = (w[i] + w[i-1] + sk2[kk] * w[i-2]) * pair2(PINF[kk], PING[kk], u);     \
    } else {                                                                      \
      n_ = (w[i] + w[i-1]) * pair2(PINF[7], PING[7], u);                          \
    }                                                                             \
    w[i].x = (OKF) ? n_.x : w[i].x;                                               \
    w[i].y = (OKG) ? n_.y : w[i].y; }

#define FIN2_                                                                     \
  f2 mx2_ = max2(max2(max2(w[8],w[9]),max2(w[10],w[11])),                         \
                 max2(max2(w[12],w[13]),max2(w[14],w[15])));                      \
  const bool zF_ = !(mx2_.x > 0.f), zG_ = !(mx2_.y > 0.f);                        \
  _Pragma("unroll") for (int k = 0; k < 8; ++k) nb2v[k] = dpp_shr1_f2(w[8 + k]);  \
  Enb_f = dpp_shr1_i(zF_ ? SENT : EnF_);                                          \
  Enb_g = dpp_shr1_i(zG_ ? SENT : EnG_);                                          \
  if (lane == 0) { Enb_f = SENT; Enb_g = SENT; }                                  \
  const int eF_ = ((__float_as_int(mx2_.x) >> 23) & 255) - 126;                   \
  const int eG_ = ((__float_as_int(mx2_.y) >> 23) & 255) - 126;                   \
  const f2 rs2_ = (f2){__int_as_float((127 - eF_) << 23),                         \
                       __int_as_float((127 - eG_) << 23)};                        \
  _Pragma("unroll") for (int k = 0; k < 8; ++k) a2[k] = w[8 + k] * rs2_;          \
  E_f = EnF_ + eF_; E_g = EnG_ + eG_; zf_f = zF_; zf_g = zG_;

#define ROUND2_NG(PINF, PING, POUTF, POUTG, PCF, PCG, TOFFN) do {                 \
  ALIGN2_ PREF2_(POUTF, POUTG, PCF, PCG, TOFFN)                                   \
  STEP2_(PINF, PING, 0) STEP2_(PINF, PING, 1)                                     \
  STEP2_(PINF, PING, 2) STEP2_(PINF, PING, 3)                                     \
  FIN2_                                                                           \
} while (0)

#define ROUND2_G(T0, PINF, PING, POUTF, POUTG, PCF, PCG, TOFFN) do {              \
  ALIGN2_ PREF2_(POUTF, POUTG, PCF, PCG, TOFFN)                                   \
  _Pragma("unroll") for (int u = 0; u < 4; ++u) {                                 \
    const int sl_ = (T0) + u;                                                     \
    const bool okf_ = (sl_ >= 1) && (sl_ <= tm);                                  \
    const bool okg_ = (sl_ >= 1) && (sl_ <= TBe);                                 \
    STEP2M_(PINF, PING, u, okf_, okg_)                                            \
  }                                                                               \
  FIN2_                                                                           \
} while (0)

__global__ __launch_bounds__(192, 1)
void ctc_pk_kernel(const float* __restrict__ logits,
                   const int*   __restrict__ labels,
                   const int*   __restrict__ input_length,
                   const int*   __restrict__ label_length,
                   const int*   __restrict__ mts_ptr,
                   float*       __restrict__ out)
{
    __shared__ __align__(16) float PFb[2][Vn * TSTR];   // fwd prob dbuf (slot = t)
    __shared__ __align__(16) float PBb[2][Vn * TSTR];   // bwd prob dbuf (slot j = time tend-1-j)

    const int b    = blockIdx.x;
    const int tid  = threadIdx.x;
    const int wid  = tid >> 6;    // 0: packed DP, 1: fwd stage, 2: bwd stage
    const int lane = tid & 63;
    const float* lg  = logits + (size_t)b * Tn * Vn;
    const int*   lab = labels + b * Ln;

    const int mts = *mts_ptr;
    const int ctc_len = (int)floorf((float)(input_length[b] * Tn) / (float)mts);
    const int tend = min(max(ctc_len, 1), Tn);
    const int tm   = tend >> 1;            // meeting time: fwd t=1..tm, gamma slots 1..TBe
    const int TBe  = tend - 1 - tm;        // gamma step count (TBe <= tm)
    const int nchF = (tm + 1 + CHUNK - 1) / CHUNK;    // fwd slots 0..tm
    const int nchG = (TBe + 1 + CHUNK - 1) / CHUNK;   // gamma slots 0..TBe

    // ---- fwd metadata: window pos i=2kk+3 (odd), state s = 8*lane-8+i ----
    int soffF[7]; float skF[7];
    #pragma unroll
    for (int kk = 0; kk < 7; ++kk) {
        const int s = 8 * lane - 5 + 2 * kk;
        int e = BLANKC; float sk = 0.f;
        if (s >= 0 && s < Sn) {
            const int li = (s - 1) >> 1;
            e = lab[li];
            if (s >= 3 && e != lab[li - 1]) sk = 1.f;
        }
        soffF[kk] = e * TSTR; skF[kk] = sk;
    }
    // ---- gamma (reversed lattice) metadata: rev-state r = 8*lane-8+i, orig s = 400-r ----
    int soffG[7]; float skG[7];
    #pragma unroll
    for (int kk = 0; kk < 7; ++kk) {
        const int r = 8 * lane - 5 + 2 * kk;   // odd window position
        int e = BLANKC; float sk = 0.f;
        if (r >= 1 && r <= 399) {
            const int li = (399 - r) >> 1;     // = (s-1)/2, s = 400-r (odd)
            e = lab[li];
            if (r >= 3 && lab[li + 1] != lab[li]) sk = 1.f;  // orig skip s->s+2
        }
        soffG[kk] = e * TSTR; skG[kk] = sk;
    }
    f2 sk2[7];
    #pragma unroll
    for (int kk = 0; kk < 7; ++kk) sk2[kk] = (f2){skF[kk], skG[kk]};

    // staging: linear probs (softmax + eps), transposed [v][slot]
    auto srow = [&](const float* row, float* Pb, int i) {
        float x[Vn]; float mm = -INFINITY;
        #pragma unroll
        for (int v = 0; v < Vn; ++v) { x[v] = row[v]; mm = fmaxf(mm, x[v]); }
        float z = 0.f;
        #pragma unroll
        for (int v = 0; v < Vn; ++v) { x[v] = __expf(x[v] - mm); z += x[v]; }
        const float rz = 1.0f / z;
        #pragma unroll
        for (int v = 0; v < Vn; ++v) Pb[v * TSTR + i] = x[v] * rz + EPSF;
    };
    auto stageF = [&](int c) {
        const int base = c * CHUNK;
        const int fill = min(CHUNK, (tm + 1) - base);
        float* Pb = PFb[c & 1];
        for (int i = lane; i < fill; i += 64)
            srow(lg + (size_t)(base + i) * Vn, Pb, i);
    };
    auto stageG = [&](int c) {
        const int base = c * CHUNK;
        const int fill = min(CHUNK, (TBe + 1) - base);
        float* Pb = PBb[c & 1];
        for (int i = lane; i < fill; i += 64)
            srow(lg + (size_t)(tend - 1 - (base + i)) * Vn, Pb, i);
    };

    if (wid == 1) stageF(0);
    if (wid == 2) stageG(0);
    __syncthreads();

    // packed per-lane BFP state
    f2 a2[8], nb2v[8];
    #pragma unroll
    for (int k = 0; k < 8; ++k) a2[k] = (f2){0.f, 0.f};
    int  E_f = 0, Enb_f = SENT, E_g = 0, Enb_g = SENT;
    bool zf_f = true, zf_g = true;
    float4 qFA[8], qGA[8], qFB[8], qGB[8];

    if (wid == 0) {
        __builtin_amdgcn_s_setprio(1);
        // fwd init (.x): alpha_0 on states 0,1 (lane 0)
        if (lane == 0) {
            a2[0].x = PFb[0][BLANKC * TSTR];
            a2[1].x = PFb[0][soffF[3]];        // lane0 kk=3 -> s=1 -> lab[0]
        }
        zf_f = (lane != 0);
        // gamma init (.y): gamma_{tend-1}[s] = p_{tend-1}[ext[s]] at s in {2ll, 2ll-1}
        const int ll = label_length[b];
        const int s1 = 2 * ll, s2 = max(2 * ll - 1, 0);
        const int r1 = 400 - s1, r2 = 400 - s2;
        #pragma unroll
        for (int k = 0; k < 8; ++k) {
            const int r = 8 * lane + k;
            if (r == r1) a2[k].y = PBb[0][BLANKC * TSTR];           // s1 even -> blank
            if (r == r2 && s2 != s1) a2[k].y = PBb[0][lab[ll - 1] * TSTR];
        }
        zf_g = !((lane == (r1 >> 3)) || (lane == (r2 >> 3)));
        #pragma unroll
        for (int k = 0; k < 8; ++k) nb2v[k] = dpp_shr1_f2(a2[k]);
        Enb_f = dpp_shr1_i(zf_f ? SENT : 0);
        Enb_g = dpp_shr1_i(zf_g ? SENT : 0);
        if (lane == 0) { Enb_f = SENT; Enb_g = SENT; }
    }

    for (int c = 0; c < nchF; ++c) {
        if (wid == 1) {
            if (c + 1 < nchF) stageF(c + 1);
        } else if (wid == 2) {
            if (c + 1 < nchG) stageG(c + 1);
        } else {
            float* PcF = PFb[c & 1];
            float* PcG = PBb[c & 1];
            const int rbase = c * CHUNK;
            const int rcnt  = min(CHUNK, (tm + 1) - rbase);
            const int nr    = (rcnt + 3) >> 2;
            const int nfull = min(nr, max(0, (TBe + 1 - rbase) >> 2));
            #pragma unroll
            for (int kk = 0; kk < 7; ++kk) {
                qFA[kk] = *(const float4*)(PcF + soffF[kk]);
                qGA[kk] = *(const float4*)(PcG + soffG[kk]);
            }
            qFA[7] = *(const float4*)(PcF + BLANKC * TSTR);
            qGA[7] = *(const float4*)(PcG + BLANKC * TSTR);

            int jj = 0;
            if (c == 0) {   // first pair guarded (slot 0 invalid for BOTH chains)
                ROUND2_G(0, qFA, qGA, qFB, qGB, PcF, PcG, 4);
                ROUND2_G(4, qFB, qGB, qFA, qGA, PcF, PcG, 8);
                jj = 2;
            }
            for (; jj + 2 <= nfull; jj += 2) {   // hot path: branchless packed
                ROUND2_NG(qFA, qGA, qFB, qGB, PcF, PcG, 4 * (jj + 1));
                ROUND2_NG(qFB, qGB, qFA, qGA, PcF, PcG, 4 * (jj + 2));
            }
            for (; jj < nr; jj += 2) {           // tail: per-chain masked
                ROUND2_G(rbase + 4 * jj,       qFA, qGA, qFB, qGB, PcF, PcG, 4 * (jj + 1));
                ROUND2_G(rbase + 4 * (jj + 1), qFB, qGB, qFA, qGA, PcF, PcG, 4 * (jj + 2));
            }
        }
        __syncthreads();
    }

    // ---- readout: P = sum_s alpha_tm[s] * gamma_tm[s] / p_tm[ext[s]] ----
    float* AFa = PBb[0]; int* ELa = (int*)(PBb[0] + 512);
    float* AFg = PBb[1]; int* ELg = (int*)(PBb[1] + 512);
    if (wid == 0) {
        #pragma unroll
        for (int k = 0; k < 8; ++k) {
            AFa[lane * 8 + k] = a2[k].x;
            AFg[lane * 8 + k] = a2[k].y;     // gamma at rev-state 8*lane+k
        }
        ELa[lane] = zf_f ? SENT : E_f;
        ELg[lane] = zf_g ? SENT : E_g;
    }
    __syncthreads();

    if (wid == 0) {
        const int lpar  = (nchF - 1) & 1;          // fwd buffer holding slot tm
        const int lslot = tm & (CHUNK - 1);
        const float* Pl = PFb[lpar];
        const int sbase = 8 * lane;
        float vA = 0.f, vB = 0.f;
        int elA = 2 * SENT, elB = 2 * SENT;
        if (sbase <= 400) {
            {   // k = 0 (gamma lane 50-lane)
                const int s = sbase;
                const int row = (s & 1) ? lab[(s - 1) >> 1] : BLANKC;
                const float p = Pl[row * TSTR + lslot];
                vA  = AFa[s] * AFg[400 - s] / p;
                elA = ELa[lane] + ELg[(400 - s) >> 3];
            }
            if (sbase + 1 <= 400) {   // k = 1..7 (gamma lane 49-lane)
                #pragma unroll
                for (int k = 1; k < 8; ++k) {
                    const int s = sbase + k;
                    if (s <= 400) {
                        const int row = (s & 1) ? lab[(s - 1) >> 1] : BLANKC;
                        const float p = Pl[row * TSTR + lslot];
                        vB += AFa[s] * AFg[400 - s] / p;
                    }
                }
                elB = ELa[lane] + ELg[(400 - sbase - 1) >> 3];
            }
        }
        const int el = max(elA, elB);
        const float v = vA * dscale(elA - el) + vB * dscale(elB - el);
        const bool val = (v > 0.f);
        int em = val ? el : 2 * SENT;
        #pragma unroll
        for (int off = 1; off < 64; off <<= 1)
            em = max(em, __shfl_xor(em, off, 64));
        float sv = val ? v * dscale(el - em) : 0.f;
        #pragma unroll
        for (int off = 1; off < 64; off <<= 1)
            sv += __shfl_xor(sv, off, 64);
        if (lane == 0) out[b] = -(__logf(sv) + (float)em * LN2F);
    }
}

extern "C" void kernel_launch(void* const* d_in, const int* in_sizes, int n_in,
                              void* d_out, int out_size, void* d_ws, size_t ws_size,
                              hipStream_t stream) {
    const float* logits       = (const float*)d_in[0];
    const int*   labels       = (const int*)d_in[1];
    const int*   input_length = (const int*)d_in[2];
    const int*   label_length = (const int*)d_in[3];
    const int*   mts          = (const int*)d_in[4];
    float* out = (float*)d_out;

    ctc_pk_kernel<<<Bn, 192, 0, stream>>>(logits, labels, input_length,
                                          label_length, mts, out);
}

// Round 14
// 81.171 us; speedup vs baseline: 1.7040x; 1.7040x over previous
//
#include <hip/hip_runtime.h>
#include <math.h>

// Problem constants: B=64, T=2000, V=29, L=200
#define Bn 64
#define Tn 2000
#define Vn 29
#define Ln 200
#define Sn 401              // 2L+1 lattice states
#define BLANKC 28
#define EPSF  1e-7f
#define CHUNK 128           // time steps of linear probs per LDS buffer
#define TSTR  132           // floats per symbol row (128 + pad, quad-aligned)
#define SENT  (-(1 << 20))  // exponent sentinel for all-zero lanes
#define LN2F  0.69314718055994531f

__device__ __forceinline__ float getc(const float4& v, int u) {
    return u == 0 ? v.x : u == 1 ? v.y : u == 2 ? v.z : v.w;
}
// Full-wave DPP shifts: lane i <- lane i-1 (shr) / i+1 (shl); bound_ctrl
// zero-fills the boundary lane. Pure VALU, ~2cyc. (HW-verified R11/R12.)
__device__ __forceinline__ float dpp_shr1_f(float x) {
    return __int_as_float(__builtin_amdgcn_update_dpp(
        0, __float_as_int(x), 0x138, 0xF, 0xF, true));
}
__device__ __forceinline__ int dpp_shr1_i(int x) {
    return __builtin_amdgcn_update_dpp(0, x, 0x138, 0xF, 0xF, true);
}
__device__ __forceinline__ float dpp_shl1_f(float x) {
    return __int_as_float(__builtin_amdgcn_update_dpp(
        0, __float_as_int(x), 0x130, 0xF, 0xF, true));
}
__device__ __forceinline__ int dpp_shl1_i(int x) {
    return __builtin_amdgcn_update_dpp(0, x, 0x130, 0xF, 0xF, true);
}
// 2^d for d in [-126,0]; anything else returns exactly 0 (flush semantics).
__device__ __forceinline__ float dscale(int d) {
    return (d > 0 || d < -126) ? 0.f : __int_as_float((127 + d) << 23);
}

// ================= forward: lane owns states 8l..8l+7 in w[0..7] =================
// per-step live exchange: only state 8l-1 (nb's current w[7]) is needed.
#define ALIGNF_                                                                  \
  const int EeF_ = zf_f ? SENT : E_f;                                            \
  const int EnF_ = max(EeF_, Enb_f);                                             \
  const float snF_ = dscale(EeF_ - EnF_), sbF_ = dscale(Enb_f - EnF_);           \
  float w[8];                                                                    \
  _Pragma("unroll") for (int k = 0; k < 8; ++k) w[k] = a_f[k] * snF_;

#define PREFF_(POUT, PC, TOFFN)                                                  \
  { const int tf_ = (TOFFN) > (CHUNK-4) ? (CHUNK-4) : (TOFFN);                   \
    _Pragma("unroll") for (int m = 0; m < 4; ++m)                                \
      POUT[m] = *(const float4*)((PC) + soffF[m] + tf_);                         \
    POUT[4] = *(const float4*)((PC) + BLANKC * TSTR + tf_); }

// descending in-place update; n7_ = neighbor state 8l-1 (live, aligned)
#define STEPF_(PIN, u) {                                                         \
    const float n7_ = dpp_shr1_f(w[7]) * sbF_;                                   \
    const float pb_ = getc(PIN[4], u);                                           \
    w[7] = (fmaf(skF[3], w[5], w[7]) + w[6]) * getc(PIN[3], u);                  \
    w[6] = (w[6] + w[5]) * pb_;                                                  \
    w[5] = (fmaf(skF[2], w[3], w[5]) + w[4]) * getc(PIN[2], u);                  \
    w[4] = (w[4] + w[3]) * pb_;                                                  \
    w[3] = (fmaf(skF[1], w[1], w[3]) + w[2]) * getc(PIN[1], u);                  \
    w[2] = (w[2] + w[1]) * pb_;                                                  \
    w[1] = (fmaf(skF[0], n7_, w[1]) + w[0]) * getc(PIN[0], u);                   \
    w[0] = (w[0] + n7_) * pb_; }

#define FINF_                                                                    \
  float mxF_ = fmaxf(fmaxf(fmaxf(w[0],w[1]),fmaxf(w[2],w[3])),                   \
                     fmaxf(fmaxf(w[4],w[5]),fmaxf(w[6],w[7])));                  \
  const bool zF_ = !(mxF_ > 0.f);                                                \
  const int eF_ = ((__float_as_int(mxF_) >> 23) & 255) - 126;                    \
  const int EnewF_ = EnF_ + eF_;                                                 \
  Enb_f = dpp_shr1_i(zF_ ? SENT : EnewF_);                                       \
  if (lane == 0) Enb_f = SENT;                                                   \
  const float rsF_ = __int_as_float((127 - eF_) << 23);                          \
  _Pragma("unroll") for (int k = 0; k < 8; ++k) a_f[k] = w[k] * rsF_;            \
  E_f = EnewF_; zf_f = zF_;

#define ROUNDF(T0, PIN, POUT, PC, TOFFN) do {                                    \
  ALIGNF_  PREFF_(POUT, PC, TOFFN)                                               \
  _Pragma("unroll") for (int u = 0; u < 4; ++u) {                                \
    const int t_ = (T0) + u;                                                     \
    if (t_ != 0 && t_ < TFe) STEPF_(PIN, u)                                      \
  }                                                                              \
  FINF_                                                                          \
} while (0)

#define ROUNDF_NG(PIN, POUT, PC, TOFFN) do {                                     \
  ALIGNF_  PREFF_(POUT, PC, TOFFN)                                               \
  STEPF_(PIN, 0) STEPF_(PIN, 1) STEPF_(PIN, 2) STEPF_(PIN, 3)                    \
  FINF_                                                                          \
} while (0)

// ================= backward (beta q-form): lane owns states 8l..8l+7 ============
// w[i] = q[i] + q[i+1] + sk(odd i)*q[i+2]; needs nb q[0], q[1] (states 8l+8, 8l+9)
#define ALIGNB_                                                                  \
  const int EeB_ = zf_b ? SENT : E_b;                                            \
  const int EnB_ = max(EeB_, Enb_b);                                             \
  const float snB_ = dscale(EeB_ - EnB_), sbB_ = dscale(Enb_b - EnB_);           \
  float w[8];                                                                    \
  _Pragma("unroll") for (int k = 0; k < 8; ++k) w[k] = a_b[k] * snB_;

#define PREFB_(POUT, PC, TOFFN)                                                  \
  { const int tf_ = (TOFFN) > (CHUNK-4) ? (CHUNK-4) : (TOFFN);                   \
    _Pragma("unroll") for (int m = 0; m < 4; ++m)                                \
      POUT[m] = *(const float4*)((PC) + soffB[m] + tf_);                         \
    POUT[4] = *(const float4*)((PC) + BLANKC * TSTR + tf_); }

#define STEPB_(PIN, u) {                                                         \
    const float pb_ = getc(PIN[4], u);                                           \
    const float q0_ = w[0] * pb_;                                                \
    const float q1_ = w[1] * getc(PIN[0], u);                                    \
    const float n8_ = dpp_shl1_f(q0_) * sbB_;                                    \
    const float n9_ = dpp_shl1_f(q1_) * sbB_;                                    \
    const float q2_ = w[2] * pb_;                                                \
    const float q3_ = w[3] * getc(PIN[1], u);                                    \
    const float q4_ = w[4] * pb_;                                                \
    const float q5_ = w[5] * getc(PIN[2], u);                                    \
    const float q6_ = w[6] * pb_;                                                \
    const float q7_ = w[7] * getc(PIN[3], u);                                    \
    w[0] = q0_ + q1_;                                                            \
    w[1] = fmaf(skB[0], q3_, q1_) + q2_;                                         \
    w[2] = q2_ + q3_;                                                            \
    w[3] = fmaf(skB[1], q5_, q3_) + q4_;                                         \
    w[4] = q4_ + q5_;                                                            \
    w[5] = fmaf(skB[2], q7_, q5_) + q6_;                                         \
    w[6] = q6_ + q7_;                                                            \
    w[7] = fmaf(skB[3], n9_, q7_) + n8_; }

#define FINB_                                                                    \
  float mxB_ = fmaxf(fmaxf(fmaxf(w[0],w[1]),fmaxf(w[2],w[3])),                   \
                     fmaxf(fmaxf(w[4],w[5]),fmaxf(w[6],w[7])));                  \
  const bool zB_ = !(mxB_ > 0.f);                                                \
  const int eB_ = ((__float_as_int(mxB_) >> 23) & 255) - 126;                    \
  const int EnewB_ = EnB_ + eB_;                                                 \
  Enb_b = dpp_shl1_i(zB_ ? SENT : EnewB_);                                       \
  if (lane == 63) Enb_b = SENT;                                                  \
  const float rsB_ = __int_as_float((127 - eB_) << 23);                          \
  _Pragma("unroll") for (int k = 0; k < 8; ++k) a_b[k] = w[k] * rsB_;            \
  E_b = EnewB_; zf_b = zB_;

#define ROUNDB(S0, PIN, POUT, PC, TOFFN) do {                                    \
  ALIGNB_  PREFB_(POUT, PC, TOFFN)                                               \
  _Pragma("unroll") for (int u = 0; u < 4; ++u) {                                \
    const int s_ = (S0) + u;                                                     \
    if (s_ < TBe) STEPB_(PIN, u)                                                 \
  }                                                                              \
  FINB_                                                                          \
} while (0)

#define ROUNDB_NG(PIN, POUT, PC, TOFFN) do {                                     \
  ALIGNB_  PREFB_(POUT, PC, TOFFN)                                               \
  STEPB_(PIN, 0) STEPB_(PIN, 1) STEPB_(PIN, 2) STEPB_(PIN, 3)                    \
  FINB_                                                                          \
} while (0)

__global__ __launch_bounds__(256, 1)
void ctc_live_kernel(const float* __restrict__ logits,
                     const int*   __restrict__ labels,
                     const int*   __restrict__ input_length,
                     const int*   __restrict__ label_length,
                     const int*   __restrict__ mts_ptr,
                     float*       __restrict__ out)
{
    __shared__ __align__(16) float PFb[2][Vn * TSTR];   // fwd prob dbuf
    __shared__ __align__(16) float PBb[2][Vn * TSTR];   // bwd prob dbuf (time-reversed)

    const int b    = blockIdx.x;
    const int tid  = threadIdx.x;
    const int wid  = tid >> 6;    // 0: fwd DP, 1: bwd DP, 2: fwd stage, 3: bwd stage
    const int lane = tid & 63;
    const float* lg  = logits + (size_t)b * Tn * Vn;
    const int*   lab = labels + b * Ln;

    const int mts = *mts_ptr;
    const int ctc_len = (int)floorf((float)(input_length[b] * Tn) / (float)mts);
    const int tend = min(max(ctc_len, 1), Tn);
    const int tm   = (tend - 1) >> 1;      // meeting point
    const int TFe  = tm + 1;               // fwd consumes slots t in [0, TFe)
    const int TBe  = tend - 1 - tm;        // bwd consumes slots i=tend-1-t in [0, TBe)
    const int nchF = (TFe + CHUNK - 1) / CHUNK;
    const int nchB = (TBe + CHUNK - 1) / CHUNK;
    const int nch2 = max(nchF, nchB);

    // ---- fwd metadata: odd states 8l+1,8l+3,8l+5,8l+7 -> label rows 4l..4l+3 ----
    int soffF[4]; float skF[4];
    #pragma unroll
    for (int m = 0; m < 4; ++m) {
        const int s = 8 * lane + 2 * m + 1;
        int e = BLANKC; float sk = 0.f;
        if (s < Sn) {
            const int li = (s - 1) >> 1;      // = 4*lane + m
            e = lab[li];
            if (s >= 3 && e != lab[li - 1]) sk = 1.f;
        }
        soffF[m] = e * TSTR; skF[m] = sk;
    }
    // ---- bwd metadata: same odd rows; skB[m] = skip into state 8l+2m+1 from +2 ----
    int soffB[4]; float skB[4];
    #pragma unroll
    for (int m = 0; m < 4; ++m) {
        const int s = 8 * lane + 2 * m + 1;
        soffB[m] = ((s < Sn) ? lab[(s - 1) >> 1] : BLANKC) * TSTR;
        const int ssrc = s + 2;               // skip source state
        float sk = 0.f;
        if (ssrc < Sn) {                      // ssrc odd, >=3 automatically
            const int li = (ssrc - 1) >> 1;
            if (lab[li] != lab[li - 1]) sk = 1.f;
        }
        skB[m] = sk;
    }

    // staging: linear probs (softmax + eps), transposed [v][slot]
    auto srow = [&](const float* row, float* Pb, int i) {
        float x[Vn]; float mm = -INFINITY;
        #pragma unroll
        for (int v = 0; v < Vn; ++v) { x[v] = row[v]; mm = fmaxf(mm, x[v]); }
        float z = 0.f;
        #pragma unroll
        for (int v = 0; v < Vn; ++v) { x[v] = __expf(x[v] - mm); z += x[v]; }
        const float rz = 1.0f / z;
        #pragma unroll
        for (int v = 0; v < Vn; ++v) Pb[v * TSTR + i] = x[v] * rz + EPSF;
    };
    auto stageF = [&](int c) {
        const int base = c * CHUNK;
        const int fill = min(CHUNK, TFe - base);
        float* Pb = PFb[c & 1];
        for (int i = lane; i < fill; i += 64)
            srow(lg + (size_t)(base + i) * Vn, Pb, i);
    };
    auto stageB = [&](int c) {
        const int base = c * CHUNK;
        const int fill = min(CHUNK, TBe - base);
        float* Pb = PBb[c & 1];
        for (int i = lane; i < fill; i += 64)
            srow(lg + (size_t)(tend - 1 - (base + i)) * Vn, Pb, i);
    };

    if (wid == 2) stageF(0);
    if (wid == 3 && TBe > 0) stageB(0);
    __syncthreads();

    // per-lane BFP state
    float a_f[8] = {0.f,0.f,0.f,0.f,0.f,0.f,0.f,0.f};
    float a_b[8] = {0.f,0.f,0.f,0.f,0.f,0.f,0.f,0.f};
    int   E_f = 0, Enb_f = SENT, E_b = 0, Enb_b = SENT;
    bool  zf_f = true, zf_b = true;
    float4 qAf[5], qBf[5], qAb[5], qBb[5];

    if (wid == 0) {
        __builtin_amdgcn_s_setprio(1);
        if (lane == 0) {
            a_f[0] = PFb[0][BLANKC * TSTR];   // alpha0[0]
            a_f[1] = PFb[0][soffF[0]];        // alpha0[1] = p0[lab[0]]
        }
        zf_f = (lane != 0);
        Enb_f = dpp_shr1_i(zf_f ? SENT : 0);
        if (lane == 0) Enb_f = SENT;
    } else if (wid == 1) {
        __builtin_amdgcn_s_setprio(1);
        const int ll = label_length[b];
        const int s1 = 2 * ll, s2 = max(2 * ll - 1, 0);
        #pragma unroll
        for (int k = 0; k < 8; ++k) {
            const int s = 8 * lane + k;
            a_b[k] = (s == s1 || s == s2) ? 0.5f : 0.f;   // beta = 1 (0.5*2^1)
        }
        E_b  = 1;
        zf_b = !(((s1 >> 3) == lane) || ((s2 >> 3) == lane));
        Enb_b = dpp_shl1_i(zf_b ? SENT : E_b);
        if (lane == 63) Enb_b = SENT;
    }

    for (int c = 0; c < nch2; ++c) {
        if (wid == 2) {
            if (c + 1 < nchF) stageF(c + 1);
        } else if (wid == 3) {
            if (c + 1 < nchB) stageB(c + 1);
        } else if (wid == 0) {
            if (c < nchF) {
                float* Pc = PFb[c & 1];
                const int rbase = c * CHUNK;
                const int rcnt  = min(CHUNK, TFe - rbase);
                const int nr    = (rcnt + 3) >> 2;
                const int nfull = min((TFe - rbase) >> 2, nr);
                #pragma unroll
                for (int m = 0; m < 4; ++m)
                    qAf[m] = *(const float4*)(Pc + soffF[m]);
                qAf[4] = *(const float4*)(Pc + BLANKC * TSTR);

                int jj = 0;
                if (c == 0) {   // first pair guarded (contains t=0)
                    ROUNDF(0, qAf, qBf, Pc, 4);
                    ROUNDF(4, qBf, qAf, Pc, 8);
                    jj = 2;
                }
                for (; jj + 2 <= nfull; jj += 2) {   // hot path: branchless
                    ROUNDF_NG(qAf, qBf, Pc, 4 * (jj + 1));
                    ROUNDF_NG(qBf, qAf, Pc, 4 * (jj + 2));
                }
                for (; jj < nr; jj += 2) {           // tail pair guarded
                    ROUNDF(rbase + 4 * jj,       qAf, qBf, Pc, 4 * (jj + 1));
                    ROUNDF(rbase + 4 * (jj + 1), qBf, qAf, Pc, 4 * (jj + 2));
                }
            }
        } else {
            if (c < nchB) {
                float* Pc = PBb[c & 1];
                const int sbase = c * CHUNK;
                const int rcnt  = min(CHUNK, TBe - sbase);
                const int nr    = (rcnt + 3) >> 2;
                const int nfull = min((TBe - sbase) >> 2, nr);
                #pragma unroll
                for (int m = 0; m < 4; ++m)
                    qAb[m] = *(const float4*)(Pc + soffB[m]);
                qAb[4] = *(const float4*)(Pc + BLANKC * TSTR);

                int jj = 0;
                for (; jj + 2 <= nfull; jj += 2) {   // hot path: branchless
                    ROUNDB_NG(qAb, qBb, Pc, 4 * (jj + 1));
                    ROUNDB_NG(qBb, qAb, Pc, 4 * (jj + 2));
                }
                for (; jj < nr; jj += 2) {           // tail pair guarded
                    ROUNDB(sbase + 4 * jj,       qAb, qBb, Pc, 4 * (jj + 1));
                    ROUNDB(sbase + 4 * (jj + 1), qBb, qAb, Pc, 4 * (jj + 2));
                }
            }
        }
        __syncthreads();
    }

    // readout: sum_s alpha_tm[s] * beta_tm[s]  (AF/EL alias the prob buffers)
    float* AFa = PFb[0];
    int*   ELa = (int*)(PFb[0] + 512);
    float* AFb = PBb[0];
    int*   ELb = (int*)(PBb[0] + 512);

    if (wid == 0) {
        #pragma unroll
        for (int k = 0; k < 8; ++k) AFa[lane * 8 + k] = a_f[k];
        ELa[lane] = zf_f ? SENT : E_f;
    } else if (wid == 1) {
        #pragma unroll
        for (int k = 0; k < 8; ++k) AFb[lane * 8 + k] = a_b[k];
        ELb[lane] = zf_b ? SENT : E_b;
    }
    __syncthreads();

    if (wid == 0) {
        float v = 0.f;
        #pragma unroll
        for (int k = 0; k < 8; ++k)
            v = fmaf(AFa[lane * 8 + k], AFb[lane * 8 + k], v);
        const int el  = ELa[lane] + ELb[lane];
        const bool val = (v > 0.f);
        int em = val ? el : (SENT * 2);
        #pragma unroll
        for (int off = 1; off < 64; off <<= 1)
            em = max(em, __shfl_xor(em, off, 64));
        float sv = val ? ldexpf(v, el - em) : 0.f;
        #pragma unroll
        for (int off = 1; off < 64; off <<= 1)
            sv += __shfl_xor(sv, off, 64);
        if (lane == 0) out[b] = -(__logf(sv) + (float)em * LN2F);
    }
}

extern "C" void kernel_launch(void* const* d_in, const int* in_sizes, int n_in,
                              void* d_out, int out_size, void* d_ws, size_t ws_size,
                              hipStream_t stream) {
    const float* logits       = (const float*)d_in[0];
    const int*   labels       = (const int*)d_in[1];
    const int*   input_length = (const int*)d_in[2];
    const int*   label_length = (const int*)d_in[3];
    const int*   mts          = (const int*)d_in[4];
    float* out = (float*)d_out;

    ctc_live_kernel<<<Bn, 256, 0, stream>>>(logits, labels, input_length,
                                            label_length, mts, out);
}